// Round 11
// baseline (246.601 us; speedup 1.0000x reference)
//
#include <hip/hip_runtime.h>

typedef __bf16 bf16;
typedef __bf16 bf16x8 __attribute__((ext_vector_type(8)));
typedef __bf16 bf16x4 __attribute__((ext_vector_type(4)));
typedef float  f32x4  __attribute__((ext_vector_type(4)));

#define SB 72    // LDS row stride (elems) for 64-wide k tiles
#define CUTOFF -18.0

__device__ __forceinline__ float silu_f(float x){
  float s = 1.f/(1.f+__expf(-x));
  return x*s;
}
__device__ __forceinline__ float silu_bwd_f(float x){
  float s = 1.f/(1.f+__expf(-x));
  float si = x*s;
  return si + s*(1.f-si);
}

// ===================== generic TMx64 MFMA GEMM body (NT), BK=64 =====================
struct MArgs {
  const bf16* A; const bf16* B;
  long sA, sB;
  int lda, ldb;
  int M, N, K;
  int mode;
  float* Cf; long sCf;
  bf16*  Cb; long sCb;
  bf16*  Cb2; long sCb2;
  bf16*  Ct;  long sCt;  int ldct;
  int ldc;
  const float* auxf; int ldax; long sAuxf;
  const bf16*  auxb; long sAuxb;
  const float* rowv; long sRowv;
  const double* cd;  long sCd;
  const float* ks;   long sKs;
  const float* clp;  long sClp;
  bf16* Q; bf16* Ko; float* Vo; const float* bqkv;   // mode 11
};

// modes: 1 Cb=acc, Cb2=silu(acc), Ct=silu(acc)^T
//        2 Cb=acc-auxf[r,c], Ct same^T
//        3 Cb=silu_bwd(auxb[r,c])*acc*rowv[r], Ct same^T
//        10 Cf=acc+auxf[r,c]*clv (A scaled by ks[k], dead k-prefix skipped)
//        11 QKV: c<256->Q, <512->Ko (+Ct=Kt), else->Vo (+bias)
template<int TM>
__device__ __forceinline__ void gemm_body(const MArgs& g, int bm, int bn, int bz,
                                          bf16* As, bf16* Bs)
{
  const int row0 = bm*TM, col0 = bn*64;
  constexpr int NI  = TM/32;
  constexpr int TPR = 256/TM;
  constexpr int EPR = 64/TPR;
  constexpr int NCH = EPR/8;

  const bf16* A = g.A + (long)bz*g.sA;
  const bf16* B = g.B + (long)bz*g.sB;
  const float* ksp = g.ks ? g.ks + (long)bz*g.sKs : (const float*)0;
  const double* cd = g.cd ? g.cd + (long)bz*g.sCd : (const double*)0;
  float* Cf = g.Cf ? g.Cf + (long)bz*g.sCf : (float*)0;
  bf16* Cb  = g.Cb ? g.Cb + (long)bz*g.sCb : (bf16*)0;
  bf16* Cb2 = g.Cb2 ? g.Cb2 + (long)bz*g.sCb2 : (bf16*)0;
  bf16* Ct  = g.Ct ? g.Ct + (long)bz*g.sCt : (bf16*)0;
  const float* auxf = g.auxf ? g.auxf + (long)bz*g.sAuxf : (const float*)0;
  const bf16*  auxb = g.auxb ? g.auxb + (long)bz*g.sAuxb : (const bf16*)0;
  const float* rowv = g.rowv ? g.rowv + (long)bz*g.sRowv : (const float*)0;

  const int tid = threadIdx.x;
  const int mode = g.mode;
  const int lane = tid & 63;
  const int w = tid >> 6;
  const int wr = (w >> 1) * (TM/2), wc = (w & 1) * 32;
  const int l15 = lane & 15;
  const int quad = lane >> 4;

  f32x4 acc[NI][2];
  #pragma unroll
  for (int i=0;i<NI;i++)
    #pragma unroll
    for (int j=0;j<2;j++)
      #pragma unroll
      for (int r=0;r<4;r++) acc[i][j][r] = 0.f;

  const int rowA = tid / TPR, kA = (tid % TPR) * EPR;
  const int rowB = tid >> 2,  kB = (tid & 3) * 16;

  int klo = 0;
  if (cd && ksp) {
    const double cref = cd[g.K-1];
    while (klo + 64 < g.K && (cref - cd[klo+63]) < CUTOFF) klo += 64;
  }

  for (int k0 = klo; k0 < g.K; k0 += 64) {
    {
      const bf16* s = A + (long)(row0+rowA)*g.lda + k0 + kA;
      bf16x8 v[NCH];
      #pragma unroll
      for (int p=0;p<NCH;p++) v[p] = *(const bf16x8*)(s + p*8);
      if (ksp) {
        #pragma unroll
        for (int p=0;p<NCH;p++)
          #pragma unroll
          for (int i=0;i<8;i++)
            v[p][i] = (bf16)((float)v[p][i] * ksp[k0+kA+p*8+i]);
      }
      #pragma unroll
      for (int p=0;p<NCH;p++) *(bf16x8*)&As[rowA*SB + kA + p*8] = v[p];
    }
    {
      const bf16* s = B + (long)(col0+rowB)*g.ldb + k0 + kB;
      *(bf16x8*)&Bs[rowB*SB + kB]     = *(const bf16x8*)s;
      *(bf16x8*)&Bs[rowB*SB + kB + 8] = *(const bf16x8*)(s+8);
    }
    __syncthreads();
    #pragma unroll
    for (int ch=0; ch<2; ch++){
      bf16x8 af[NI], bf2[2];
      #pragma unroll
      for (int i=0;i<NI;i++) af[i]  = *(const bf16x8*)&As[(wr + i*16 + l15)*SB + ch*32 + quad*8];
      #pragma unroll
      for (int j=0;j<2;j++) bf2[j] = *(const bf16x8*)&Bs[(wc + j*16 + l15)*SB + ch*32 + quad*8];
      #pragma unroll
      for (int i=0;i<NI;i++)
        #pragma unroll
        for (int j=0;j<2;j++)
          acc[i][j] = __builtin_amdgcn_mfma_f32_16x16x32_bf16(af[i], bf2[j], acc[i][j], 0, 0, 0);
    }
    __syncthreads();
  }

  float clv = 0.f;
  if (mode == 10) clv = *(g.clp + (long)bz*g.sClp);

  #pragma unroll
  for (int i=0;i<NI;i++){
    const int rb = row0 + wr + i*16 + quad*4;
    #pragma unroll
    for (int j=0;j<2;j++){
      const int c = col0 + wc + j*16 + l15;
      bf16 tv[4]; bool doT = false;
      #pragma unroll
      for (int reg=0; reg<4; reg++){
        const int r = rb + reg;
        float v = acc[i][j][reg];
        const long co = (long)r*g.ldc + c;
        switch (mode) {
          case 1: {
            Cb[co]  = (bf16)v;
            bf16 sv = (bf16)silu_f(v);
            Cb2[co] = sv;
            tv[reg] = sv; doT = true;
          } break;
          case 2: {
            bf16 o = (bf16)(v - auxf[(long)r*g.ldax + c]);
            Cb[co] = o; tv[reg] = o; doT = true;
          } break;
          case 3: {
            bf16 o = (bf16)(silu_bwd_f((float)auxb[(long)r*g.ldax + c]) * v * rowv[r]);
            Cb[co] = o; tv[reg] = o; doT = true;
          } break;
          case 10: {
            Cf[co] = v + auxf[(long)r*g.ldax + c]*clv;
          } break;
          case 11: {
            float o = v + g.bqkv[c];
            if (c < 256)      g.Q [(long)r*256 + c]       = (bf16)o;
            else if (c < 512) { g.Ko[(long)r*256 + (c-256)] = (bf16)o; tv[reg] = (bf16)o; doT = true; }
            else              g.Vo[(long)r*256 + (c-512)] = o;
          } break;
        }
      }
      if (doT && Ct) {
        bf16x4 t4 = { tv[0], tv[1], tv[2], tv[3] };
        if (mode == 11) {
          const int b = rb / g.ldct, l = rb % g.ldct;
          *(bf16x4*)&Ct[(long)b*g.sCt + (long)(c-256)*g.ldct + l] = t4;
        } else {
          *(bf16x4*)&Ct[(long)c*g.ldct + rb] = t4;
        }
      }
    }
  }
}

__global__ __launch_bounds__(256)
void mfma_gemm128(MArgs g){
  __shared__ __align__(16) bf16 smem[(128+64)*SB];
  gemm_body<128>(g, blockIdx.x, blockIdx.y, blockIdx.z, smem, smem + 128*SB);
}

__global__ __launch_bounds__(256)
void mfma_gemm64(MArgs g){
  __shared__ __align__(16) bf16 smem[(64+64)*SB];
  gemm_body<64>(g, blockIdx.x, blockIdx.y, blockIdx.z, smem, smem + 64*SB);
}

// ===================== banded P producer body (64m x 128l tiles) =====================
struct PArgs {
  const bf16 *A, *B1;
  long sA, sB1;
  const double* cd; long sCd;
  const float* lrv; long sLr;
  bf16* P;
};

template<int KS64, int ISLR>
__device__ __forceinline__ void pgen_body(const PArgs& g, int mt, int slot, int bz,
                                          bf16* As, bf16* Bs)
{
  const int m0 = mt*64;
  const int l0 = (m0 & ~127) - slot*128;
  if (l0 < 0) return;
  const double* cd = g.cd + (long)bz*g.sCd;
  const int lref = (l0+127 < m0) ? (l0+127) : m0;
  if (cd[m0] - cd[lref] < CUTOFF) return;

  const int K1 = KS64*64;
  const bf16* A  = g.A  + (long)bz*g.sA;
  const bf16* B1 = g.B1 + (long)bz*g.sB1;
  const float* lrv = ISLR ? (g.lrv + (long)bz*g.sLr) : (const float*)0;

  const int tid = threadIdx.x;
  const int lane = tid & 63, w = tid >> 6;
  const int wr = (w>>1)*32, wc = (w&1)*64;
  const int l15 = lane & 15, quad = lane >> 4;
  const int rowA = tid >> 2, kA = (tid & 3) * 16;
  const int rowB = tid >> 1, kB = (tid & 1) * 32;

  f32x4 O[2][4];
  #pragma unroll
  for (int i=0;i<2;i++)
    #pragma unroll
    for (int j=0;j<4;j++)
      #pragma unroll
      for (int r=0;r<4;r++) O[i][j][r] = 0.f;

  for (int ks=0; ks<KS64; ks++){
    const int k0 = ks*64;
    {
      const bf16* s = A + (long)(m0+rowA)*K1 + k0 + kA;
      *(bf16x8*)&As[rowA*SB + kA]     = *(const bf16x8*)s;
      *(bf16x8*)&As[rowA*SB + kA + 8] = *(const bf16x8*)(s+8);
    }
    {
      const bf16* s = B1 + (long)(l0+rowB)*K1 + k0 + kB;
      #pragma unroll
      for (int p=0;p<4;p++) *(bf16x8*)&Bs[rowB*SB + kB + p*8] = *(const bf16x8*)(s + p*8);
    }
    __syncthreads();
    #pragma unroll
    for (int ch=0; ch<2; ch++){
      bf16x8 af[2], bfr[4];
      #pragma unroll
      for (int i=0;i<2;i++) af[i]  = *(const bf16x8*)&As[(wr + i*16 + l15)*SB + ch*32 + quad*8];
      #pragma unroll
      for (int j=0;j<4;j++) bfr[j] = *(const bf16x8*)&Bs[(wc + j*16 + l15)*SB + ch*32 + quad*8];
      #pragma unroll
      for (int i=0;i<2;i++)
        #pragma unroll
        for (int j=0;j<4;j++)
          O[i][j] = __builtin_amdgcn_mfma_f32_16x16x32_bf16(af[i], bfr[j], O[i][j], 0, 0, 0);
    }
    __syncthreads();
  }

  bf16* Pt = g.P + (((long)bz*32 + mt)*3 + slot) * (64*128);
  float cl[4], lv[4];
  #pragma unroll
  for (int j=0;j<4;j++){
    const int l = l0 + wc + j*16 + l15;
    cl[j] = (float)cd[l];
    if (ISLR) lv[j] = lrv[l];
  }
  #pragma unroll
  for (int i=0;i<2;i++)
    #pragma unroll
    for (int reg=0; reg<4; reg++){
      const int mloc = wr + i*16 + quad*4 + reg;
      const int m = m0 + mloc;
      const float cm = (float)cd[m];
      #pragma unroll
      for (int j=0;j<4;j++){
        const int lloc = wc + j*16 + l15;
        const int l = l0 + lloc;
        float v = -O[i][j][reg] * __expf(cm - cl[j]);
        if (ISLR) v *= lv[j];
        if (l > m) v = 0.f;
        Pt[mloc*128 + lloc] = (bf16)v;
      }
    }
}

// merged: z<4 -> A1 GEMM (64-tile, mode 3), z>=4 -> pgen1 (slot = y, y<3)
__global__ __launch_bounds__(256)
void a1_pgen1(MArgs ga, PArgs gp){
  __shared__ __align__(16) bf16 smem[192*SB];
  const int z = blockIdx.z;
  if (z < 4) {
    gemm_body<64>(ga, blockIdx.x, blockIdx.y, z, smem, smem + 64*SB);
  } else {
    if (blockIdx.y >= 3) return;
    pgen_body<4,0>(gp, blockIdx.x, blockIdx.y, z - 4, smem, smem + 64*SB);
  }
}

// merged: z<4 -> pgen2 (y<3), z>=4 -> wnext dual GEMM
__global__ __launch_bounds__(256)
void pgen2_wnext(PArgs gp, MArgs g1, MArgs g2){
  __shared__ __align__(16) bf16 smem[192*SB];
  const int z = blockIdx.z;
  if (z < 4) {
    if (blockIdx.y >= 3) return;
    pgen_body<8,1>(gp, blockIdx.x, blockIdx.y, z, smem, smem + 64*SB);
  } else {
    const int z2 = z - 4;
    const MArgs& g = (z2 < 4) ? g1 : g2;
    const int bz = z2 & 3;
    if ((int)blockIdx.x*128 >= g.M || (int)blockIdx.y*64 >= g.N) return;
    gemm_body<128>(g, blockIdx.x, blockIdx.y, bz, smem, smem + 128*SB);
  }
}

// ===================== consumer: O = wdc[m]*(A.W^T) + sum_slots P.B2 ====================
struct CArgs {
  const bf16 *A, *W, *P, *B2;
  long sA, sW, sB2;
  int ldb2;
  const double* cd; long sCd;
  const float* wdc; long sWdc;
  float* Cf; long sCf;
  bf16* Cb; long sCb;
  int ldc;
};

template<int KS64, int SILU, int ZSPLIT>
__global__ __launch_bounds__(256)
void cons(CArgs g)
{
  const int mt = blockIdx.x;
  const int m0 = mt*64, n0 = blockIdx.y*128;
  const int bz   = ZSPLIT ? (blockIdx.z >> 1) : blockIdx.z;
  const int half = ZSPLIT ? (blockIdx.z & 1)  : 0;
  const int K1 = KS64*64;
  const bf16* A  = g.A  + (long)bz*g.sA;
  const bf16* W  = g.W  + (long)bz*g.sW;
  const bf16* B2 = g.B2 + (long)bz*g.sB2;
  const double* cd = g.cd + (long)bz*g.sCd;
  const float* wdc = g.wdc + (long)bz*g.sWdc;

  const int tid = threadIdx.x;
  const int lane = tid & 63, w = tid >> 6;
  const int wr = (w>>1)*32, wc = (w&1)*64;
  const int l15 = lane & 15, quad = lane >> 4;
  const int rowA = tid >> 2, kA = (tid & 3) * 16;
  const int rowB = tid >> 1, kB = (tid & 1) * 32;

  bool alive[3];
  int nalive = 0;
  #pragma unroll
  for (int s=0;s<3;s++){
    const int l0 = (m0 & ~127) - s*128;
    bool a = (l0 >= 0);
    if (a) {
      const int lref = (l0+127 < m0) ? (l0+127) : m0;
      a = (cd[m0] - cd[lref] >= CUTOFF);
    }
    alive[s] = a; nalive += a ? 1 : 0;
  }
  if (ZSPLIT && half == 1 && nalive == 0) return;

  __shared__ __align__(16) bf16 As[64*SB];
  __shared__ __align__(16) bf16 Bs[128*SB];

  f32x4 O[2][4];
  #pragma unroll
  for (int i=0;i<2;i++)
    #pragma unroll
    for (int j=0;j<4;j++)
      #pragma unroll
      for (int r=0;r<4;r++) O[i][j][r] = 0.f;

  if (half == 0) {
    for (int ks=0; ks<KS64; ks++){
      const int k0 = ks*64;
      {
        const bf16* s = A + (long)(m0+rowA)*K1 + k0 + kA;
        *(bf16x8*)&As[rowA*SB + kA]     = *(const bf16x8*)s;
        *(bf16x8*)&As[rowA*SB + kA + 8] = *(const bf16x8*)(s+8);
      }
      {
        const bf16* s = W + (long)(n0+rowB)*K1 + k0 + kB;
        #pragma unroll
        for (int p=0;p<4;p++) *(bf16x8*)&Bs[rowB*SB + kB + p*8] = *(const bf16x8*)(s + p*8);
      }
      __syncthreads();
      #pragma unroll
      for (int ch=0; ch<2; ch++){
        bf16x8 af[2], bfr[4];
        #pragma unroll
        for (int i=0;i<2;i++) af[i]  = *(const bf16x8*)&As[(wr + i*16 + l15)*SB + ch*32 + quad*8];
        #pragma unroll
        for (int j=0;j<4;j++) bfr[j] = *(const bf16x8*)&Bs[(wc + j*16 + l15)*SB + ch*32 + quad*8];
        #pragma unroll
        for (int i=0;i<2;i++)
          #pragma unroll
          for (int j=0;j<4;j++)
            O[i][j] = __builtin_amdgcn_mfma_f32_16x16x32_bf16(af[i], bfr[j], O[i][j], 0, 0, 0);
      }
      __syncthreads();
    }
    #pragma unroll
    for (int i=0;i<2;i++)
      #pragma unroll
      for (int reg=0; reg<4; reg++){
        const float s = wdc[m0 + wr + i*16 + quad*4 + reg];
        #pragma unroll
        for (int j=0;j<4;j++) O[i][j][reg] *= s;
      }
  }

  if (!ZSPLIT || half == 1) {
    for (int s=0; s<3; s++){
      if (!alive[s]) continue;
      const int l0 = (m0 & ~127) - s*128;
      const bf16* Pt = g.P + (((long)bz*32 + mt)*3 + s) * (64*128);
      for (int hk=0; hk<2; hk++){
        {
          const bf16* sp = Pt + (long)rowA*128 + hk*64 + kA;
          *(bf16x8*)&As[rowA*SB + kA]     = *(const bf16x8*)sp;
          *(bf16x8*)&As[rowA*SB + kA + 8] = *(const bf16x8*)(sp+8);
        }
        {
          const bf16* sp = B2 + (long)(n0+rowB)*g.ldb2 + l0 + hk*64 + kB;
          #pragma unroll
          for (int p=0;p<4;p++) *(bf16x8*)&Bs[rowB*SB + kB + p*8] = *(const bf16x8*)(sp + p*8);
        }
        __syncthreads();
        #pragma unroll
        for (int ch=0; ch<2; ch++){
          bf16x8 af[2], bfr[4];
          #pragma unroll
          for (int i=0;i<2;i++) af[i]  = *(const bf16x8*)&As[(wr + i*16 + l15)*SB + ch*32 + quad*8];
          #pragma unroll
          for (int j=0;j<4;j++) bfr[j] = *(const bf16x8*)&Bs[(wc + j*16 + l15)*SB + ch*32 + quad*8];
          #pragma unroll
          for (int i=0;i<2;i++)
            #pragma unroll
            for (int j=0;j<4;j++)
              O[i][j] = __builtin_amdgcn_mfma_f32_16x16x32_bf16(af[i], bfr[j], O[i][j], 0, 0, 0);
        }
        __syncthreads();
      }
    }
  }

  #pragma unroll
  for (int i=0;i<2;i++){
    const int rb = m0 + wr + i*16 + quad*4;
    #pragma unroll
    for (int j=0;j<4;j++){
      const int c = n0 + wc + j*16 + l15;
      #pragma unroll
      for (int reg=0; reg<4; reg++){
        const long co = (long)(rb+reg)*g.ldc + c;
        if (ZSPLIT)     unsafeAtomicAdd(&g.Cf[(long)bz*g.sCf + co], O[i][j][reg]);
        else if (SILU)  g.Cb[(long)bz*g.sCb + co] = (bf16)silu_f(O[i][j][reg]);
        else            g.Cf[(long)bz*g.sCf + co] = O[i][j][reg];
      }
    }
  }
}

// ===================== front matter: 1D job ladder =====================
// [0,1024)   conv x -> xb
// [1024,1280) conv W1 -> W1b
// [1280,1536) conv W2 -> W2b
// [1536,2560) zero out0
// [2560,2608) transpose Wq/Wk/Wv -> Wqkvt
// [2608,2736) transpose W2 -> W2t
// [2736,4784) scalar_proj (4 rows/block)
struct FrontArgs {
  const float *x, *W1, *W2, *Wq, *Wk, *Wv;
  bf16 *xb, *W1b, *W2b, *Wqkvt, *W2t;
  float* out0;
  const float *wlr, *blr, *wwd, *bwd, *lbl, *lbw;
  float *lr, *lw;
  long LD4, HD4, HD;   // Bn*LD, Bn*HD, HD
};

__global__ __launch_bounds__(256)
void front_kernel(FrontArgs f)
{
  __shared__ bf16 t[64][72];
  const int bid = blockIdx.x;
  const int tid = threadIdx.x;

  if (bid < 1536) {   // conv jobs
    const float* src; bf16* dst; long n; long base;
    if (bid < 1024)      { src = f.x;  dst = f.xb;  n = f.LD4; base = (long)bid*2048; }
    else if (bid < 1280) { src = f.W1; dst = f.W1b; n = f.HD4; base = (long)(bid-1024)*2048; }
    else                 { src = f.W2; dst = f.W2b; n = f.HD4; base = (long)(bid-1280)*2048; }
    long i = base + (long)tid*8;
    if (i >= n) return;
    float4 a = *(const float4*)&src[i];
    float4 b = *(const float4*)&src[i+4];
    bf16x8 o;
    o[0]=(bf16)a.x; o[1]=(bf16)a.y; o[2]=(bf16)a.z; o[3]=(bf16)a.w;
    o[4]=(bf16)b.x; o[5]=(bf16)b.y; o[6]=(bf16)b.z; o[7]=(bf16)b.w;
    *(bf16x8*)&dst[i] = o;
    return;
  }
  if (bid < 2560) {   // zero out0
    long i = (long)(bid-1536)*2048 + (long)tid*8;
    float4 z = {0.f,0.f,0.f,0.f};
    *(float4*)&f.out0[i]   = z;
    *(float4*)&f.out0[i+4] = z;
    return;
  }
  if (bid < 2736) {   // transposes
    const float* ip; bf16* op; int R, C; int r0, c0;
    if (bid < 2608) {
      const int r = bid - 2560;          // 48 blocks: z*16 + y*4 + x
      const int z = r >> 4, rem = r & 15;
      ip = z==0 ? f.Wq : (z==1 ? f.Wk : f.Wv);
      op = f.Wqkvt + (long)z*256*256;
      R = 256; C = 256;
      r0 = (rem & 3)*64; c0 = (rem >> 2)*64;
    } else {
      const int r = bid - 2608;          // 128 blocks: b*32 + y*4 + x
      const int b = r >> 5, rem = r & 31;
      ip = f.W2 + (long)b*f.HD;
      op = f.W2t + (long)b*f.HD;
      R = 256; C = 512;
      r0 = (rem & 3)*64; c0 = (rem >> 2)*64;
    }
    const int lr_ = tid>>2, lc = (tid&3)*16;
    #pragma unroll
    for (int q=0;q<4;q++){
      float4 a = *(const float4*)&ip[(long)(r0+lr_)*C + c0+lc + q*4];
      t[lr_][lc+q*4+0] = (bf16)a.x; t[lr_][lc+q*4+1] = (bf16)a.y;
      t[lr_][lc+q*4+2] = (bf16)a.z; t[lr_][lc+q*4+3] = (bf16)a.w;
    }
    __syncthreads();
    const int oc = tid>>2, orr = (tid&3)*16;
    bf16x8 u, v;
    #pragma unroll
    for (int i=0;i<8;i++){ u[i] = t[orr+i][oc]; v[i] = t[orr+8+i][oc]; }
    *(bf16x8*)&op[(long)(c0+oc)*R + r0+orr]   = u;
    *(bf16x8*)&op[(long)(c0+oc)*R + r0+orr+8] = v;
    return;
  }
  {   // scalar_proj: 4 rows per block
    const int row  = (bid-2736)*4 + (tid >> 6);
    const int lane = tid & 63;
    const float4 a = ((const float4*)(f.x + (long)row*256))[lane];
    const float4 u = ((const float4*)f.wlr)[lane];
    const float4 w = ((const float4*)f.wwd)[lane];
    float d1 = a.x*u.x + a.y*u.y + a.z*u.z + a.w*u.w;
    float d2 = a.x*w.x + a.y*w.y + a.z*w.z + a.w*w.w;
    #pragma unroll
    for (int off=32; off; off>>=1) {
      d1 += __shfl_down(d1, off);
      d2 += __shfl_down(d2, off);
    }
    if (lane == 0) {
      float s1 = 1.f/(1.f+expf(-(d1 + f.blr[0])));
      f.lr[row] = expf(f.lbl[0]) * s1;
      float s2 = 1.f/(1.f+expf(-(d2 + f.bwd[0])));
      f.lw[row] = logf(1.f - expf(f.lbw[0]) * s2);
    }
  }
}

// blocks 0..3: per-batch fp64 scan + derived; block 4: bias concat
__global__ __launch_bounds__(256)
void cumsum_kernel(const float* __restrict__ lw, const float* __restrict__ lr,
                   double* __restrict__ cd, float* __restrict__ wdc,
                   float* __restrict__ se1, float* __restrict__ se2, int L,
                   const float* __restrict__ bq, const float* __restrict__ bk,
                   const float* __restrict__ bv, float* __restrict__ bqkv)
{
  const int b = blockIdx.x;
  const int t = threadIdx.x;
  if (b == 4) {
    for (int i = t; i < 768; i += 256)
      bqkv[i] = (i<256) ? bq[i] : ((i<512) ? bk[i-256] : bv[i-512]);
    return;
  }
  const float* lwb = lw + (long)b*L;
  __shared__ double sum_s[256];
  double loc[8];
  double s = 0.0;
  #pragma unroll
  for (int i=0;i<8;i++){ s += (double)lwb[t*8+i]; loc[i] = s; }
  sum_s[t] = s;
  __syncthreads();
  for (int off=1; off<256; off<<=1){
    double v = 0.0;
    if (t >= off) v = sum_s[t-off];
    __syncthreads();
    sum_s[t] += v;
    __syncthreads();
  }
  const double prefix = (t > 0) ? sum_s[t-1] : 0.0;
  const double total  = sum_s[255];
  #pragma unroll
  for (int i=0;i<8;i++){
    double c = prefix + loc[i];
    long idx = (long)b*L + t*8 + i;
    cd[idx]  = c;
    wdc[idx] = (float)exp(c);
    double e = exp(total - c);
    se1[idx] = (float)(-e);
    se2[idx] = (float)(-e) * lr[idx];
  }
}

extern "C" void kernel_launch(void* const* d_in, const int* in_sizes, int n_in,
                              void* d_out, int out_size, void* d_ws, size_t ws_size,
                              hipStream_t stream)
{
  const int Bn = 4, L = 2048, D = 256, H = 512;
  const long LD = (long)L*D, LH = (long)L*H, HD = (long)H*D;

  const float* x   = (const float*)d_in[0];
  const float* W1  = (const float*)d_in[1];
  const float* W2  = (const float*)d_in[2];
  const float* Wq  = (const float*)d_in[3];
  const float* bq  = (const float*)d_in[4];
  const float* Wk  = (const float*)d_in[5];
  const float* bk  = (const float*)d_in[6];
  const float* Wv  = (const float*)d_in[7];
  const float* bv  = (const float*)d_in[8];
  const float* wlr = (const float*)d_in[9];
  const float* blr = (const float*)d_in[10];
  const float* wwd = (const float*)d_in[11];
  const float* bwd = (const float*)d_in[12];
  const float* lbl = (const float*)d_in[13];
  const float* lbw = (const float*)d_in[14];
  (void)in_sizes; (void)n_in; (void)out_size; (void)ws_size;

  float* out0 = (float*)d_out;            // Z2_      [B,L,D]
  float* out1 = out0 + (long)Bn*LD;       // W1_next  [B,H,D]
  float* out2 = out1 + (long)Bn*HD;       // W2_next  [B,D,H]

  char* wsp = (char*)d_ws;
  size_t off = 0;
  auto alloc = [&](size_t bytes)->void*{
    void* p = wsp + off; off += (bytes + 255) & ~(size_t)255; return p;
  };
  bf16* xb    = (bf16*)alloc((size_t)Bn*LD*2);
  bf16* Wqkvt = (bf16*)alloc((size_t)3*D*D*2);
  float* bqkv = (float*)alloc((size_t)3*D*4);
  bf16* W1b  = (bf16*)alloc((size_t)Bn*HD*2);
  bf16* W2b  = (bf16*)alloc((size_t)Bn*HD*2);
  bf16* W2t  = (bf16*)alloc((size_t)Bn*HD*2);
  bf16* Qb   = (bf16*)alloc((size_t)Bn*LD*2);
  bf16* Kb   = (bf16*)alloc((size_t)Bn*LD*2);
  bf16* Kt   = (bf16*)alloc((size_t)Bn*LD*2);
  float* Vf  = (float*)alloc((size_t)Bn*LD*4);
  bf16* Z1b  = (bf16*)alloc((size_t)Bn*LH*2);
  bf16* X2b  = (bf16*)alloc((size_t)Bn*LH*2);
  bf16* X2t  = (bf16*)alloc((size_t)Bn*LH*2);
  bf16* gZb  = (bf16*)alloc((size_t)Bn*LD*2);
  bf16* gZt  = (bf16*)alloc((size_t)Bn*LD*2);
  bf16* A1b  = (bf16*)alloc((size_t)Bn*LH*2);
  bf16* A1t  = (bf16*)alloc((size_t)Bn*LH*2);
  bf16* X2_b = (bf16*)alloc((size_t)Bn*LH*2);
  bf16* Pb1  = (bf16*)alloc((size_t)Bn*32*3*64*128*2);
  bf16* Pb2  = (bf16*)alloc((size_t)Bn*32*3*64*128*2);
  float* lrb = (float*)alloc((size_t)Bn*L*4);
  float* lwb = (float*)alloc((size_t)Bn*L*4);
  float* wdc = (float*)alloc((size_t)Bn*L*4);
  float* se1 = (float*)alloc((size_t)Bn*L*4);
  float* se2 = (float*)alloc((size_t)Bn*L*4);
  double* cdb = (double*)alloc((size_t)Bn*L*8);

  auto run128 = [&](const MArgs& g, int Z){
    dim3 grid(g.M/128, g.N/64, Z);
    mfma_gemm128<<<grid, 256, 0, stream>>>(g);
  };
  auto run64 = [&](const MArgs& g, int Z){
    dim3 grid(g.M/64, g.N/64, Z);
    mfma_gemm64<<<grid, 256, 0, stream>>>(g);
  };

  // ---- 1. front matter (conv + transposes + scalar_proj + out0 zero)
  {
    FrontArgs f{};
    f.x = x; f.W1 = W1; f.W2 = W2; f.Wq = Wq; f.Wk = Wk; f.Wv = Wv;
    f.xb = xb; f.W1b = W1b; f.W2b = W2b; f.Wqkvt = Wqkvt; f.W2t = W2t;
    f.out0 = out0;
    f.wlr = wlr; f.blr = blr; f.wwd = wwd; f.bwd = bwd; f.lbl = lbl; f.lbw = lbw;
    f.lr = lrb; f.lw = lwb;
    f.LD4 = Bn*LD; f.HD4 = Bn*HD; f.HD = HD;
    front_kernel<<<dim3(4784), 256, 0, stream>>>(f);
  }
  // ---- 2. cumsum + bias concat
  cumsum_kernel<<<dim3(5), 256, 0, stream>>>(lwb, lrb, cdb, wdc, se1, se2, L, bq, bk, bv, bqkv);

  // ---- 3. fused QKV (M = B*L, N = 768); Kt via Ct
  {
    MArgs g{}; g.A = xb; g.lda = D; g.B = Wqkvt; g.ldb = D;
    g.M = Bn*L; g.N = 3*D; g.K = D; g.mode = 11; g.ldc = 0;
    g.Q = Qb; g.Ko = Kb; g.Vo = Vf; g.bqkv = bqkv;
    g.Ct = Kt; g.sCt = LD; g.ldct = L;
    run128(g, 1);
  }
  // ---- 4. Z1 = K.W1^T ; X2 = silu(Z1); X2t via Ct
  {
    MArgs g{}; g.A = Kb; g.lda = D; g.sA = LD; g.B = W1b; g.ldb = D; g.sB = HD;
    g.M = L; g.N = H; g.K = D; g.mode = 1; g.ldc = H;
    g.Cb = Z1b; g.sCb = LH; g.Cb2 = X2b; g.sCb2 = LH;
    g.Ct = X2t; g.sCt = LH; g.ldct = L; run64(g, Bn);
  }
  // ---- 5. gZ2 = X2.W2^T - V; gZt via Ct
  {
    MArgs g{}; g.A = X2b; g.lda = H; g.sA = LH; g.B = W2b; g.ldb = H; g.sB = HD;
    g.M = L; g.N = D; g.K = H; g.mode = 2; g.ldc = D;
    g.auxf = Vf; g.ldax = D; g.sAuxf = LD; g.Cb = gZb; g.sCb = LD;
    g.Ct = gZt; g.sCt = LD; g.ldct = L; run64(g, Bn);
  }
  // ---- 6. A1 GEMM + pgen1 (independent) in one launch
  {
    MArgs ga{}; ga.A = gZb; ga.lda = D; ga.sA = LD; ga.B = W2t; ga.ldb = D; ga.sB = HD;
    ga.M = L; ga.N = H; ga.K = D; ga.mode = 3; ga.ldc = H;
    ga.auxb = Z1b; ga.ldax = H; ga.sAuxb = LH; ga.rowv = lrb; ga.sRowv = L;
    ga.Cb = A1b; ga.sCb = LH;
    ga.Ct = A1t; ga.sCt = LH; ga.ldct = L;

    PArgs gp{};
    gp.A = Qb; gp.sA = LD; gp.B1 = Kb; gp.sB1 = LD;
    gp.cd = cdb; gp.sCd = L; gp.P = Pb1;

    a1_pgen1<<<dim3(32, 8, 8), 256, 0, stream>>>(ga, gp);
  }
  // ---- 7. cons1: X2_ = silu( wdc[m]*(Q.W1^T) + sum P1.A1t )
  {
    CArgs c{};
    c.A = Qb; c.sA = LD; c.W = W1b; c.sW = HD;
    c.P = Pb1; c.B2 = A1t; c.sB2 = LH; c.ldb2 = L;
    c.cd = cdb; c.sCd = L; c.wdc = wdc; c.sWdc = L;
    c.Cb = X2_b; c.sCb = LH; c.ldc = H;
    cons<4,1,0><<<dim3(32, H/128, Bn), 256, 0, stream>>>(c);
  }
  // ---- 8. pgen2 + W-next (independent) in one launch
  {
    PArgs gp{};
    gp.A = X2_b; gp.sA = LH; gp.B1 = X2b; gp.sB1 = LH;
    gp.cd = cdb; gp.sCd = L; gp.lrv = lrb; gp.sLr = L; gp.P = Pb2;

    MArgs g1{}; g1.A = A1t; g1.lda = L; g1.sA = LH; g1.B = Kt; g1.ldb = L; g1.sB = LD;
    g1.M = H; g1.N = D; g1.K = L; g1.mode = 10; g1.ldc = D;
    g1.ks = se1; g1.sKs = L; g1.cd = cdb; g1.sCd = L;
    g1.auxf = W1; g1.ldax = D; g1.sAuxf = HD; g1.clp = wdc + (L-1); g1.sClp = L;
    g1.Cf = out1; g1.sCf = HD;

    MArgs g2{}; g2.A = gZt; g2.lda = L; g2.sA = LD; g2.B = X2t; g2.ldb = L; g2.sB = LH;
    g2.M = D; g2.N = H; g2.K = L; g2.mode = 10; g2.ldc = H;
    g2.ks = se2; g2.sKs = L; g2.cd = cdb; g2.sCd = L;
    g2.auxf = W2; g2.ldax = H; g2.sAuxf = HD; g2.clp = wdc + (L-1); g2.sClp = L;
    g2.Cf = out2; g2.sCf = HD;

    pgen2_wnext<<<dim3(32, 8, 12), 256, 0, stream>>>(gp, g1, g2);
  }
  // ---- 9. cons2: out0 += wdc[m]*(X2_.W2^T) + sum P2.gZt   (z-split, atomic)
  {
    CArgs c{};
    c.A = X2_b; c.sA = LH; c.W = W2b; c.sW = HD;
    c.P = Pb2; c.B2 = gZt; c.sB2 = LD; c.ldb2 = L;
    c.cd = cdb; c.sCd = L; c.wdc = wdc; c.sWdc = L;
    c.Cf = out0; c.sCf = LD; c.ldc = D;
    cons<8,0,1><<<dim3(32, D/128, Bn*2), 256, 0, stream>>>(c);
  }
}

// Round 12
// 233.379 us; speedup vs baseline: 1.0567x; 1.0567x over previous
//
#include <hip/hip_runtime.h>

typedef __bf16 bf16;
typedef __bf16 bf16x8 __attribute__((ext_vector_type(8)));
typedef __bf16 bf16x4 __attribute__((ext_vector_type(4)));
typedef float  f32x4  __attribute__((ext_vector_type(4)));

#define SB 72    // LDS row stride (elems) for 64-wide k tiles
#define CUTOFF -18.0

__device__ __forceinline__ float silu_f(float x){
  float s = 1.f/(1.f+__expf(-x));
  return x*s;
}
__device__ __forceinline__ float silu_bwd_f(float x){
  float s = 1.f/(1.f+__expf(-x));
  float si = x*s;
  return si + s*(1.f-si);
}

// ===================== generic TMx64 MFMA GEMM (NT), BK=64 (R8-proven) =====================
struct MArgs {
  const bf16* A; const bf16* B;
  long sA, sB;
  int lda, ldb;
  int M, N, K;
  int mode;
  float* Cf; long sCf;
  bf16*  Cb; long sCb;
  bf16*  Cb2; long sCb2;
  bf16*  Ct;  long sCt;  int ldct;   // optional transposed output
  int ldc;
  const float* auxf; int ldax; long sAuxf;
  const bf16*  auxb; long sAuxb;
  const float* rowv; long sRowv;
  const double* cd;  long sCd;
  const float* ks;   long sKs;
  const float* clp;  long sClp;
  bf16* Q; bf16* Ko; float* Vo; const float* bqkv;   // mode 11
};

// modes: 1 Cb=acc, Cb2=silu(acc), Ct=silu(acc)^T
//        2 Cb=acc-auxf[r,c], Ct same^T
//        3 Cb=silu_bwd(auxb[r,c])*acc*rowv[r], Ct same^T
//        10 Cf=acc+auxf[r,c]*clv (A scaled by ks[k], dead k-prefix skipped)
//        11 QKV: c<256->Q, <512->Ko (+Ct=Kt), else->Vo (+bias)
template<int TM>
__device__ __forceinline__ void gemm_body(const MArgs& g, int bm, int bn, int bz)
{
  const int row0 = bm*TM, col0 = bn*64;
  constexpr int NI  = TM/32;
  constexpr int TPR = 256/TM;
  constexpr int EPR = 64/TPR;
  constexpr int NCH = EPR/8;

  const bf16* A = g.A + (long)bz*g.sA;
  const bf16* B = g.B + (long)bz*g.sB;
  const float* ksp = g.ks ? g.ks + (long)bz*g.sKs : (const float*)0;
  const double* cd = g.cd ? g.cd + (long)bz*g.sCd : (const double*)0;
  float* Cf = g.Cf ? g.Cf + (long)bz*g.sCf : (float*)0;
  bf16* Cb  = g.Cb ? g.Cb + (long)bz*g.sCb : (bf16*)0;
  bf16* Cb2 = g.Cb2 ? g.Cb2 + (long)bz*g.sCb2 : (bf16*)0;
  bf16* Ct  = g.Ct ? g.Ct + (long)bz*g.sCt : (bf16*)0;
  const float* auxf = g.auxf ? g.auxf + (long)bz*g.sAuxf : (const float*)0;
  const bf16*  auxb = g.auxb ? g.auxb + (long)bz*g.sAuxb : (const bf16*)0;
  const float* rowv = g.rowv ? g.rowv + (long)bz*g.sRowv : (const float*)0;

  const int tid = threadIdx.x;
  const int mode = g.mode;
  const int lane = tid & 63;
  const int w = tid >> 6;
  const int wr = (w >> 1) * (TM/2), wc = (w & 1) * 32;
  const int l15 = lane & 15;
  const int quad = lane >> 4;

  __shared__ __align__(16) bf16 As[TM*SB];
  __shared__ __align__(16) bf16 Bs[64*SB];

  f32x4 acc[NI][2];
  #pragma unroll
  for (int i=0;i<NI;i++)
    #pragma unroll
    for (int j=0;j<2;j++)
      #pragma unroll
      for (int r=0;r<4;r++) acc[i][j][r] = 0.f;

  const int rowA = tid / TPR, kA = (tid % TPR) * EPR;
  const int rowB = tid >> 2,  kB = (tid & 3) * 16;

  int klo = 0;
  if (cd && ksp) {
    const double cref = cd[g.K-1];
    while (klo + 64 < g.K && (cref - cd[klo+63]) < CUTOFF) klo += 64;
  }

  for (int k0 = klo; k0 < g.K; k0 += 64) {
    {
      const bf16* s = A + (long)(row0+rowA)*g.lda + k0 + kA;
      bf16x8 v[NCH];
      #pragma unroll
      for (int p=0;p<NCH;p++) v[p] = *(const bf16x8*)(s + p*8);
      if (ksp) {
        #pragma unroll
        for (int p=0;p<NCH;p++)
          #pragma unroll
          for (int i=0;i<8;i++)
            v[p][i] = (bf16)((float)v[p][i] * ksp[k0+kA+p*8+i]);
      }
      #pragma unroll
      for (int p=0;p<NCH;p++) *(bf16x8*)&As[rowA*SB + kA + p*8] = v[p];
    }
    {
      const bf16* s = B + (long)(col0+rowB)*g.ldb + k0 + kB;
      *(bf16x8*)&Bs[rowB*SB + kB]     = *(const bf16x8*)s;
      *(bf16x8*)&Bs[rowB*SB + kB + 8] = *(const bf16x8*)(s+8);
    }
    __syncthreads();
    #pragma unroll
    for (int ch=0; ch<2; ch++){
      bf16x8 af[NI], bf2[2];
      #pragma unroll
      for (int i=0;i<NI;i++) af[i]  = *(const bf16x8*)&As[(wr + i*16 + l15)*SB + ch*32 + quad*8];
      #pragma unroll
      for (int j=0;j<2;j++) bf2[j] = *(const bf16x8*)&Bs[(wc + j*16 + l15)*SB + ch*32 + quad*8];
      #pragma unroll
      for (int i=0;i<NI;i++)
        #pragma unroll
        for (int j=0;j<2;j++)
          acc[i][j] = __builtin_amdgcn_mfma_f32_16x16x32_bf16(af[i], bf2[j], acc[i][j], 0, 0, 0);
    }
    __syncthreads();
  }

  float clv = 0.f;
  if (mode == 10) clv = *(g.clp + (long)bz*g.sClp);

  #pragma unroll
  for (int i=0;i<NI;i++){
    const int rb = row0 + wr + i*16 + quad*4;
    #pragma unroll
    for (int j=0;j<2;j++){
      const int c = col0 + wc + j*16 + l15;
      bf16 tv[4]; bool doT = false;
      #pragma unroll
      for (int reg=0; reg<4; reg++){
        const int r = rb + reg;
        float v = acc[i][j][reg];
        const long co = (long)r*g.ldc + c;
        switch (mode) {
          case 1: {
            Cb[co]  = (bf16)v;
            bf16 sv = (bf16)silu_f(v);
            Cb2[co] = sv;
            tv[reg] = sv; doT = true;
          } break;
          case 2: {
            bf16 o = (bf16)(v - auxf[(long)r*g.ldax + c]);
            Cb[co] = o; tv[reg] = o; doT = true;
          } break;
          case 3: {
            bf16 o = (bf16)(silu_bwd_f((float)auxb[(long)r*g.ldax + c]) * v * rowv[r]);
            Cb[co] = o; tv[reg] = o; doT = true;
          } break;
          case 10: {
            Cf[co] = v + auxf[(long)r*g.ldax + c]*clv;
          } break;
          case 11: {
            float o = v + g.bqkv[c];
            if (c < 256)      g.Q [(long)r*256 + c]       = (bf16)o;
            else if (c < 512) { g.Ko[(long)r*256 + (c-256)] = (bf16)o; tv[reg] = (bf16)o; doT = true; }
            else              g.Vo[(long)r*256 + (c-512)] = o;
          } break;
        }
      }
      if (doT && Ct) {
        bf16x4 t4 = { tv[0], tv[1], tv[2], tv[3] };
        if (mode == 11) {
          const int b = rb / g.ldct, l = rb % g.ldct;
          *(bf16x4*)&Ct[(long)b*g.sCt + (long)(c-256)*g.ldct + l] = t4;
        } else {
          *(bf16x4*)&Ct[(long)c*g.ldct + rb] = t4;
        }
      }
    }
  }
}

__global__ __launch_bounds__(256)
void mfma_gemm128(MArgs g){ gemm_body<128>(g, blockIdx.x, blockIdx.y, blockIdx.z); }

__global__ __launch_bounds__(256)
void mfma_gemm64(MArgs g){ gemm_body<64>(g, blockIdx.x, blockIdx.y, blockIdx.z); }

// dual-job W-next: z<4 -> g1 (batch z), z>=4 -> g2 (batch z-4)
__global__ __launch_bounds__(256)
void wnext_gemm(MArgs g1, MArgs g2){
  const int z = blockIdx.z;
  const MArgs& g = (z < 4) ? g1 : g2;
  const int bz = z & 3;
  if ((int)blockIdx.x*128 >= g.M || (int)blockIdx.y*64 >= g.N) return;
  gemm_body<128>(g, blockIdx.x, blockIdx.y, bz);
}

// ===================== banded P producer (64m x 128l tiles) =====================
// P[m,l] = -(A[m].B1[l]) * exp(cd[m]-cd[l]) * (l<=m) * (ISLR? lr[l]:1)
struct PArgs {
  const bf16 *A, *B1;
  long sA, sB1;
  const double* cd; long sCd;
  const float* lrv; long sLr;
  bf16* P;
};

template<int KS64, int ISLR>
__global__ __launch_bounds__(256)
void pgen(PArgs g)
{
  const int mt = blockIdx.x, slot = blockIdx.y, bz = blockIdx.z;
  const int m0 = mt*64;
  const int l0 = (m0 & ~127) - slot*128;
  if (l0 < 0) return;
  const double* cd = g.cd + (long)bz*g.sCd;
  const int lref = (l0+127 < m0) ? (l0+127) : m0;
  if (cd[m0] - cd[lref] < CUTOFF) return;

  const int K1 = KS64*64;
  const bf16* A  = g.A  + (long)bz*g.sA;
  const bf16* B1 = g.B1 + (long)bz*g.sB1;
  const float* lrv = ISLR ? (g.lrv + (long)bz*g.sLr) : (const float*)0;

  const int tid = threadIdx.x;
  const int lane = tid & 63, w = tid >> 6;
  const int wr = (w>>1)*32, wc = (w&1)*64;
  const int l15 = lane & 15, quad = lane >> 4;
  const int rowA = tid >> 2, kA = (tid & 3) * 16;
  const int rowB = tid >> 1, kB = (tid & 1) * 32;

  __shared__ __align__(16) bf16 As[64*SB];
  __shared__ __align__(16) bf16 Bs[128*SB];

  f32x4 O[2][4];
  #pragma unroll
  for (int i=0;i<2;i++)
    #pragma unroll
    for (int j=0;j<4;j++)
      #pragma unroll
      for (int r=0;r<4;r++) O[i][j][r] = 0.f;

  for (int ks=0; ks<KS64; ks++){
    const int k0 = ks*64;
    {
      const bf16* s = A + (long)(m0+rowA)*K1 + k0 + kA;
      *(bf16x8*)&As[rowA*SB + kA]     = *(const bf16x8*)s;
      *(bf16x8*)&As[rowA*SB + kA + 8] = *(const bf16x8*)(s+8);
    }
    {
      const bf16* s = B1 + (long)(l0+rowB)*K1 + k0 + kB;
      #pragma unroll
      for (int p=0;p<4;p++) *(bf16x8*)&Bs[rowB*SB + kB + p*8] = *(const bf16x8*)(s + p*8);
    }
    __syncthreads();
    #pragma unroll
    for (int ch=0; ch<2; ch++){
      bf16x8 af[2], bfr[4];
      #pragma unroll
      for (int i=0;i<2;i++) af[i]  = *(const bf16x8*)&As[(wr + i*16 + l15)*SB + ch*32 + quad*8];
      #pragma unroll
      for (int j=0;j<4;j++) bfr[j] = *(const bf16x8*)&Bs[(wc + j*16 + l15)*SB + ch*32 + quad*8];
      #pragma unroll
      for (int i=0;i<2;i++)
        #pragma unroll
        for (int j=0;j<4;j++)
          O[i][j] = __builtin_amdgcn_mfma_f32_16x16x32_bf16(af[i], bfr[j], O[i][j], 0, 0, 0);
    }
    __syncthreads();
  }

  bf16* Pt = g.P + (((long)bz*32 + mt)*3 + slot) * (64*128);
  float cl[4], lv[4];
  #pragma unroll
  for (int j=0;j<4;j++){
    const int l = l0 + wc + j*16 + l15;
    cl[j] = (float)cd[l];
    if (ISLR) lv[j] = lrv[l];
  }
  #pragma unroll
  for (int i=0;i<2;i++)
    #pragma unroll
    for (int reg=0; reg<4; reg++){
      const int mloc = wr + i*16 + quad*4 + reg;
      const int m = m0 + mloc;
      const float cm = (float)cd[m];
      #pragma unroll
      for (int j=0;j<4;j++){
        const int lloc = wc + j*16 + l15;
        const int l = l0 + lloc;
        float v = -O[i][j][reg] * __expf(cm - cl[j]);
        if (ISLR) v *= lv[j];
        if (l > m) v = 0.f;
        Pt[mloc*128 + lloc] = (bf16)v;
      }
    }
}

// ===================== consumer: O = wdc[m]*(A.W^T) + sum_slots P.B2 ====================
// 64m x 64n tiles (small tiles -> 1024-block grids for latency overlap).
// ZSPLIT: half0 = cross term, half1 = band term, fp32 atomic into Cf.
struct CArgs {
  const bf16 *A, *W, *P, *B2;
  long sA, sW, sB2;
  int ldb2;
  const double* cd; long sCd;
  const float* wdc; long sWdc;
  float* Cf; long sCf;
  bf16* Cb; long sCb;
  int ldc;
};

template<int KS64, int SILU, int ZSPLIT>
__global__ __launch_bounds__(256)
void cons(CArgs g)
{
  const int mt = blockIdx.x;
  const int m0 = mt*64, n0 = blockIdx.y*64;
  const int bz   = ZSPLIT ? (blockIdx.z >> 1) : blockIdx.z;
  const int half = ZSPLIT ? (blockIdx.z & 1)  : 0;
  const int K1 = KS64*64;
  const bf16* A  = g.A  + (long)bz*g.sA;
  const bf16* W  = g.W  + (long)bz*g.sW;
  const bf16* B2 = g.B2 + (long)bz*g.sB2;
  const double* cd = g.cd + (long)bz*g.sCd;
  const float* wdc = g.wdc + (long)bz*g.sWdc;

  const int tid = threadIdx.x;
  const int lane = tid & 63, w = tid >> 6;
  const int wr = (w>>1)*32, wc = (w&1)*32;
  const int l15 = lane & 15, quad = lane >> 4;
  const int rowA = tid >> 2, kA = (tid & 3) * 16;   // 64-row tiles, 16 elems/thr

  // which band slots are alive (block-uniform)
  bool alive[3];
  int nalive = 0;
  #pragma unroll
  for (int s=0;s<3;s++){
    const int l0 = (m0 & ~127) - s*128;
    bool a = (l0 >= 0);
    if (a) {
      const int lref = (l0+127 < m0) ? (l0+127) : m0;
      a = (cd[m0] - cd[lref] >= CUTOFF);
    }
    alive[s] = a; nalive += a ? 1 : 0;
  }
  if (ZSPLIT && half == 1 && nalive == 0) return;

  __shared__ __align__(16) bf16 As[64*SB];
  __shared__ __align__(16) bf16 Bs[64*SB];

  f32x4 O[2][2];
  #pragma unroll
  for (int i=0;i<2;i++)
    #pragma unroll
    for (int j=0;j<2;j++)
      #pragma unroll
      for (int r=0;r<4;r++) O[i][j][r] = 0.f;

  // ---- cross phase: O = A . W^T, scaled by wdc[m]
  if (half == 0) {
    for (int ks=0; ks<KS64; ks++){
      const int k0 = ks*64;
      {
        const bf16* s = A + (long)(m0+rowA)*K1 + k0 + kA;
        *(bf16x8*)&As[rowA*SB + kA]     = *(const bf16x8*)s;
        *(bf16x8*)&As[rowA*SB + kA + 8] = *(const bf16x8*)(s+8);
      }
      {
        const bf16* s = W + (long)(n0+rowA)*K1 + k0 + kA;
        *(bf16x8*)&Bs[rowA*SB + kA]     = *(const bf16x8*)s;
        *(bf16x8*)&Bs[rowA*SB + kA + 8] = *(const bf16x8*)(s+8);
      }
      __syncthreads();
      #pragma unroll
      for (int ch=0; ch<2; ch++){
        bf16x8 af[2], bfr[2];
        #pragma unroll
        for (int i=0;i<2;i++) af[i]  = *(const bf16x8*)&As[(wr + i*16 + l15)*SB + ch*32 + quad*8];
        #pragma unroll
        for (int j=0;j<2;j++) bfr[j] = *(const bf16x8*)&Bs[(wc + j*16 + l15)*SB + ch*32 + quad*8];
        #pragma unroll
        for (int i=0;i<2;i++)
          #pragma unroll
          for (int j=0;j<2;j++)
            O[i][j] = __builtin_amdgcn_mfma_f32_16x16x32_bf16(af[i], bfr[j], O[i][j], 0, 0, 0);
      }
      __syncthreads();
    }
    #pragma unroll
    for (int i=0;i<2;i++)
      #pragma unroll
      for (int reg=0; reg<4; reg++){
        const float s = wdc[m0 + wr + i*16 + quad*4 + reg];
        #pragma unroll
        for (int j=0;j<2;j++) O[i][j][reg] *= s;
      }
  }

  // ---- band phase: O += P . B2
  if (!ZSPLIT || half == 1) {
    for (int s=0; s<3; s++){
      if (!alive[s]) continue;
      const int l0 = (m0 & ~127) - s*128;
      const bf16* Pt = g.P + (((long)bz*32 + mt)*3 + s) * (64*128);
      for (int hk=0; hk<2; hk++){
        {
          const bf16* sp = Pt + (long)rowA*128 + hk*64 + kA;
          *(bf16x8*)&As[rowA*SB + kA]     = *(const bf16x8*)sp;
          *(bf16x8*)&As[rowA*SB + kA + 8] = *(const bf16x8*)(sp+8);
        }
        {
          const bf16* sp = B2 + (long)(n0+rowA)*g.ldb2 + l0 + hk*64 + kA;
          *(bf16x8*)&Bs[rowA*SB + kA]     = *(const bf16x8*)sp;
          *(bf16x8*)&Bs[rowA*SB + kA + 8] = *(const bf16x8*)(sp+8);
        }
        __syncthreads();
        #pragma unroll
        for (int ch=0; ch<2; ch++){
          bf16x8 af[2], bfr[2];
          #pragma unroll
          for (int i=0;i<2;i++) af[i]  = *(const bf16x8*)&As[(wr + i*16 + l15)*SB + ch*32 + quad*8];
          #pragma unroll
          for (int j=0;j<2;j++) bfr[j] = *(const bf16x8*)&Bs[(wc + j*16 + l15)*SB + ch*32 + quad*8];
          #pragma unroll
          for (int i=0;i<2;i++)
            #pragma unroll
            for (int j=0;j<2;j++)
              O[i][j] = __builtin_amdgcn_mfma_f32_16x16x32_bf16(af[i], bfr[j], O[i][j], 0, 0, 0);
        }
        __syncthreads();
      }
    }
  }

  // ---- epilogue
  #pragma unroll
  for (int i=0;i<2;i++){
    const int rb = m0 + wr + i*16 + quad*4;
    #pragma unroll
    for (int j=0;j<2;j++){
      const int c = n0 + wc + j*16 + l15;
      #pragma unroll
      for (int reg=0; reg<4; reg++){
        const long co = (long)(rb+reg)*g.ldc + c;
        if (ZSPLIT)     unsafeAtomicAdd(&g.Cf[(long)bz*g.sCf + co], O[i][j][reg]);
        else if (SILU)  g.Cb[(long)bz*g.sCb + co] = (bf16)silu_f(O[i][j][reg]);
        else            g.Cf[(long)bz*g.sCf + co] = O[i][j][reg];
      }
    }
  }
}

// ===================== front matter: 1D job ladder =====================
// [0,1024)   conv x -> xb
// [1024,1280) conv W1 -> W1b
// [1280,1536) conv W2 -> W2b
// [1536,2560) zero out0
// [2560,2608) transpose Wq/Wk/Wv -> Wqkvt
// [2608,2736) transpose W2 -> W2t
// [2736,4784) scalar_proj (4 rows/block)
struct FrontArgs {
  const float *x, *W1, *W2, *Wq, *Wk, *Wv;
  bf16 *xb, *W1b, *W2b, *Wqkvt, *W2t;
  float* out0;
  const float *wlr, *blr, *wwd, *bwd, *lbl, *lbw;
  float *lr, *lw;
  long LD4, HD4, HD;
};

__global__ __launch_bounds__(256)
void front_kernel(FrontArgs f)
{
  __shared__ bf16 t[64][72];
  const int bid = blockIdx.x;
  const int tid = threadIdx.x;

  if (bid < 1536) {
    const float* src; bf16* dst; long n; long base;
    if (bid < 1024)      { src = f.x;  dst = f.xb;  n = f.LD4; base = (long)bid*2048; }
    else if (bid < 1280) { src = f.W1; dst = f.W1b; n = f.HD4; base = (long)(bid-1024)*2048; }
    else                 { src = f.W2; dst = f.W2b; n = f.HD4; base = (long)(bid-1280)*2048; }
    long i = base + (long)tid*8;
    if (i >= n) return;
    float4 a = *(const float4*)&src[i];
    float4 b = *(const float4*)&src[i+4];
    bf16x8 o;
    o[0]=(bf16)a.x; o[1]=(bf16)a.y; o[2]=(bf16)a.z; o[3]=(bf16)a.w;
    o[4]=(bf16)b.x; o[5]=(bf16)b.y; o[6]=(bf16)b.z; o[7]=(bf16)b.w;
    *(bf16x8*)&dst[i] = o;
    return;
  }
  if (bid < 2560) {
    long i = (long)(bid-1536)*2048 + (long)tid*8;
    float4 z = {0.f,0.f,0.f,0.f};
    *(float4*)&f.out0[i]   = z;
    *(float4*)&f.out0[i+4] = z;
    return;
  }
  if (bid < 2736) {
    const float* ip; bf16* op; int R, C; int r0, c0;
    if (bid < 2608) {
      const int r = bid - 2560;
      const int z = r >> 4, rem = r & 15;
      ip = z==0 ? f.Wq : (z==1 ? f.Wk : f.Wv);
      op = f.Wqkvt + (long)z*256*256;
      R = 256; C = 256;
      r0 = (rem & 3)*64; c0 = (rem >> 2)*64;
    } else {
      const int r = bid - 2608;
      const int b = r >> 5, rem = r & 31;
      ip = f.W2 + (long)b*f.HD;
      op = f.W2t + (long)b*f.HD;
      R = 256; C = 512;
      r0 = (rem & 3)*64; c0 = (rem >> 2)*64;
    }
    const int lr_ = tid>>2, lc = (tid&3)*16;
    #pragma unroll
    for (int q=0;q<4;q++){
      float4 a = *(const float4*)&ip[(long)(r0+lr_)*C + c0+lc + q*4];
      t[lr_][lc+q*4+0] = (bf16)a.x; t[lr_][lc+q*4+1] = (bf16)a.y;
      t[lr_][lc+q*4+2] = (bf16)a.z; t[lr_][lc+q*4+3] = (bf16)a.w;
    }
    __syncthreads();
    const int oc = tid>>2, orr = (tid&3)*16;
    bf16x8 u, v;
    #pragma unroll
    for (int i=0;i<8;i++){ u[i] = t[orr+i][oc]; v[i] = t[orr+8+i][oc]; }
    *(bf16x8*)&op[(long)(c0+oc)*R + r0+orr]   = u;
    *(bf16x8*)&op[(long)(c0+oc)*R + r0+orr+8] = v;
    return;
  }
  {
    const int row  = (bid-2736)*4 + (tid >> 6);
    const int lane = tid & 63;
    const float4 a = ((const float4*)(f.x + (long)row*256))[lane];
    const float4 u = ((const float4*)f.wlr)[lane];
    const float4 w = ((const float4*)f.wwd)[lane];
    float d1 = a.x*u.x + a.y*u.y + a.z*u.z + a.w*u.w;
    float d2 = a.x*w.x + a.y*w.y + a.z*w.z + a.w*w.w;
    #pragma unroll
    for (int off=32; off; off>>=1) {
      d1 += __shfl_down(d1, off);
      d2 += __shfl_down(d2, off);
    }
    if (lane == 0) {
      float s1 = 1.f/(1.f+expf(-(d1 + f.blr[0])));
      f.lr[row] = expf(f.lbl[0]) * s1;
      float s2 = 1.f/(1.f+expf(-(d2 + f.bwd[0])));
      f.lw[row] = logf(1.f - expf(f.lbw[0]) * s2);
    }
  }
}

// blocks 0..3: per-batch fp64 scan + derived; block 4: bias concat
__global__ __launch_bounds__(256)
void cumsum_kernel(const float* __restrict__ lw, const float* __restrict__ lr,
                   double* __restrict__ cd, float* __restrict__ wdc,
                   float* __restrict__ se1, float* __restrict__ se2, int L,
                   const float* __restrict__ bq, const float* __restrict__ bk,
                   const float* __restrict__ bv, float* __restrict__ bqkv)
{
  const int b = blockIdx.x;
  const int t = threadIdx.x;
  if (b == 4) {
    for (int i = t; i < 768; i += 256)
      bqkv[i] = (i<256) ? bq[i] : ((i<512) ? bk[i-256] : bv[i-512]);
    return;
  }
  const float* lwb = lw + (long)b*L;
  __shared__ double sum_s[256];
  double loc[8];
  double s = 0.0;
  #pragma unroll
  for (int i=0;i<8;i++){ s += (double)lwb[t*8+i]; loc[i] = s; }
  sum_s[t] = s;
  __syncthreads();
  for (int off=1; off<256; off<<=1){
    double v = 0.0;
    if (t >= off) v = sum_s[t-off];
    __syncthreads();
    sum_s[t] += v;
    __syncthreads();
  }
  const double prefix = (t > 0) ? sum_s[t-1] : 0.0;
  const double total  = sum_s[255];
  #pragma unroll
  for (int i=0;i<8;i++){
    double c = prefix + loc[i];
    long idx = (long)b*L + t*8 + i;
    cd[idx]  = c;
    wdc[idx] = (float)exp(c);
    double e = exp(total - c);
    se1[idx] = (float)(-e);
    se2[idx] = (float)(-e) * lr[idx];
  }
}

extern "C" void kernel_launch(void* const* d_in, const int* in_sizes, int n_in,
                              void* d_out, int out_size, void* d_ws, size_t ws_size,
                              hipStream_t stream)
{
  const int Bn = 4, L = 2048, D = 256, H = 512;
  const long LD = (long)L*D, LH = (long)L*H, HD = (long)H*D;

  const float* x   = (const float*)d_in[0];
  const float* W1  = (const float*)d_in[1];
  const float* W2  = (const float*)d_in[2];
  const float* Wq  = (const float*)d_in[3];
  const float* bq  = (const float*)d_in[4];
  const float* Wk  = (const float*)d_in[5];
  const float* bk  = (const float*)d_in[6];
  const float* Wv  = (const float*)d_in[7];
  const float* bv  = (const float*)d_in[8];
  const float* wlr = (const float*)d_in[9];
  const float* blr = (const float*)d_in[10];
  const float* wwd = (const float*)d_in[11];
  const float* bwd = (const float*)d_in[12];
  const float* lbl = (const float*)d_in[13];
  const float* lbw = (const float*)d_in[14];
  (void)in_sizes; (void)n_in; (void)out_size; (void)ws_size;

  float* out0 = (float*)d_out;            // Z2_      [B,L,D]
  float* out1 = out0 + (long)Bn*LD;       // W1_next  [B,H,D]
  float* out2 = out1 + (long)Bn*HD;       // W2_next  [B,D,H]

  char* wsp = (char*)d_ws;
  size_t off = 0;
  auto alloc = [&](size_t bytes)->void*{
    void* p = wsp + off; off += (bytes + 255) & ~(size_t)255; return p;
  };
  bf16* xb    = (bf16*)alloc((size_t)Bn*LD*2);
  bf16* Wqkvt = (bf16*)alloc((size_t)3*D*D*2);
  float* bqkv = (float*)alloc((size_t)3*D*4);
  bf16* W1b  = (bf16*)alloc((size_t)Bn*HD*2);
  bf16* W2b  = (bf16*)alloc((size_t)Bn*HD*2);
  bf16* W2t  = (bf16*)alloc((size_t)Bn*HD*2);
  bf16* Qb   = (bf16*)alloc((size_t)Bn*LD*2);
  bf16* Kb   = (bf16*)alloc((size_t)Bn*LD*2);
  bf16* Kt   = (bf16*)alloc((size_t)Bn*LD*2);
  float* Vf  = (float*)alloc((size_t)Bn*LD*4);
  bf16* Z1b  = (bf16*)alloc((size_t)Bn*LH*2);
  bf16* X2b  = (bf16*)alloc((size_t)Bn*LH*2);
  bf16* X2t  = (bf16*)alloc((size_t)Bn*LH*2);
  bf16* gZb  = (bf16*)alloc((size_t)Bn*LD*2);
  bf16* gZt  = (bf16*)alloc((size_t)Bn*LD*2);
  bf16* A1b  = (bf16*)alloc((size_t)Bn*LH*2);
  bf16* A1t  = (bf16*)alloc((size_t)Bn*LH*2);
  bf16* X2_b = (bf16*)alloc((size_t)Bn*LH*2);
  bf16* Pb1  = (bf16*)alloc((size_t)Bn*32*3*64*128*2);
  bf16* Pb2  = (bf16*)alloc((size_t)Bn*32*3*64*128*2);
  float* lrb = (float*)alloc((size_t)Bn*L*4);
  float* lwb = (float*)alloc((size_t)Bn*L*4);
  float* wdc = (float*)alloc((size_t)Bn*L*4);
  float* se1 = (float*)alloc((size_t)Bn*L*4);
  float* se2 = (float*)alloc((size_t)Bn*L*4);
  double* cdb = (double*)alloc((size_t)Bn*L*8);

  auto run128 = [&](const MArgs& g, int Z){
    dim3 grid(g.M/128, g.N/64, Z);
    mfma_gemm128<<<grid, 256, 0, stream>>>(g);
  };
  auto run64 = [&](const MArgs& g, int Z){
    dim3 grid(g.M/64, g.N/64, Z);
    mfma_gemm64<<<grid, 256, 0, stream>>>(g);
  };

  // ---- 1. front matter (conv + transposes + scalar_proj + out0 zero)
  {
    FrontArgs f{};
    f.x = x; f.W1 = W1; f.W2 = W2; f.Wq = Wq; f.Wk = Wk; f.Wv = Wv;
    f.xb = xb; f.W1b = W1b; f.W2b = W2b; f.Wqkvt = Wqkvt; f.W2t = W2t;
    f.out0 = out0;
    f.wlr = wlr; f.blr = blr; f.wwd = wwd; f.bwd = bwd; f.lbl = lbl; f.lbw = lbw;
    f.lr = lrb; f.lw = lwb;
    f.LD4 = Bn*LD; f.HD4 = Bn*HD; f.HD = HD;
    front_kernel<<<dim3(4784), 256, 0, stream>>>(f);
  }
  // ---- 2. cumsum + bias concat
  cumsum_kernel<<<dim3(5), 256, 0, stream>>>(lwb, lrb, cdb, wdc, se1, se2, L, bq, bk, bv, bqkv);

  // ---- 3. fused QKV (M = B*L, N = 768); Kt via Ct
  {
    MArgs g{}; g.A = xb; g.lda = D; g.B = Wqkvt; g.ldb = D;
    g.M = Bn*L; g.N = 3*D; g.K = D; g.mode = 11; g.ldc = 0;
    g.Q = Qb; g.Ko = Kb; g.Vo = Vf; g.bqkv = bqkv;
    g.Ct = Kt; g.sCt = LD; g.ldct = L;
    run128(g, 1);
  }
  // ---- 4. Z1 = K.W1^T ; X2 = silu(Z1); X2t via Ct
  {
    MArgs g{}; g.A = Kb; g.lda = D; g.sA = LD; g.B = W1b; g.ldb = D; g.sB = HD;
    g.M = L; g.N = H; g.K = D; g.mode = 1; g.ldc = H;
    g.Cb = Z1b; g.sCb = LH; g.Cb2 = X2b; g.sCb2 = LH;
    g.Ct = X2t; g.sCt = LH; g.ldct = L; run64(g, Bn);
  }
  // ---- 5. gZ2 = X2.W2^T - V; gZt via Ct
  {
    MArgs g{}; g.A = X2b; g.lda = H; g.sA = LH; g.B = W2b; g.ldb = H; g.sB = HD;
    g.M = L; g.N = D; g.K = H; g.mode = 2; g.ldc = D;
    g.auxf = Vf; g.ldax = D; g.sAuxf = LD; g.Cb = gZb; g.sCb = LD;
    g.Ct = gZt; g.sCt = LD; g.ldct = L; run64(g, Bn);
  }
  // ---- 6. A1 = silu_bwd(Z1)*(gZ2.W2)*lr; A1t via Ct
  {
    MArgs g{}; g.A = gZb; g.lda = D; g.sA = LD; g.B = W2t; g.ldb = D; g.sB = HD;
    g.M = L; g.N = H; g.K = D; g.mode = 3; g.ldc = H;
    g.auxb = Z1b; g.ldax = H; g.sAuxb = LH; g.rowv = lrb; g.sRowv = L;
    g.Cb = A1b; g.sCb = LH;
    g.Ct = A1t; g.sCt = LH; g.ldct = L; run64(g, Bn);
  }
  // ---- 7. P1 banded tiles
  {
    PArgs p{};
    p.A = Qb; p.sA = LD; p.B1 = Kb; p.sB1 = LD;
    p.cd = cdb; p.sCd = L; p.P = Pb1;
    pgen<4,0><<<dim3(32,3,Bn), 256, 0, stream>>>(p);
  }
  // ---- 8. cons1: X2_ = silu( wdc[m]*(Q.W1^T) + sum P1.A1t )
  {
    CArgs c{};
    c.A = Qb; c.sA = LD; c.W = W1b; c.sW = HD;
    c.P = Pb1; c.B2 = A1t; c.sB2 = LH; c.ldb2 = L;
    c.cd = cdb; c.sCd = L; c.wdc = wdc; c.sWdc = L;
    c.Cb = X2_b; c.sCb = LH; c.ldc = H;
    cons<4,1,0><<<dim3(32, H/64, Bn), 256, 0, stream>>>(c);
  }
  // ---- 9. P2 banded tiles
  {
    PArgs p{};
    p.A = X2_b; p.sA = LH; p.B1 = X2b; p.sB1 = LH;
    p.cd = cdb; p.sCd = L; p.lrv = lrb; p.sLr = L; p.P = Pb2;
    pgen<8,1><<<dim3(32,3,Bn), 256, 0, stream>>>(p);
  }
  // ---- 10. cons2: out0 += wdc[m]*(X2_.W2^T) + sum P2.gZt   (z-split, atomic)
  {
    CArgs c{};
    c.A = X2_b; c.sA = LH; c.W = W2b; c.sW = HD;
    c.P = Pb2; c.B2 = gZt; c.sB2 = LD; c.ldb2 = L;
    c.cd = cdb; c.sCd = L; c.wdc = wdc; c.sWdc = L;
    c.Cf = out0; c.sCf = LD; c.ldc = D;
    cons<8,0,1><<<dim3(32, D/64, Bn*2), 256, 0, stream>>>(c);
  }
  // ---- 11. W1_next + W2_next in one launch
  {
    MArgs g1{}; g1.A = A1t; g1.lda = L; g1.sA = LH; g1.B = Kt; g1.ldb = L; g1.sB = LD;
    g1.M = H; g1.N = D; g1.K = L; g1.mode = 10; g1.ldc = D;
    g1.ks = se1; g1.sKs = L; g1.cd = cdb; g1.sCd = L;
    g1.auxf = W1; g1.ldax = D; g1.sAuxf = HD; g1.clp = wdc + (L-1); g1.sClp = L;
    g1.Cf = out1; g1.sCf = HD;

    MArgs g2{}; g2.A = gZt; g2.lda = L; g2.sA = LD; g2.B = X2t; g2.ldb = L; g2.sB = LH;
    g2.M = D; g2.N = H; g2.K = L; g2.mode = 10; g2.ldc = H;
    g2.ks = se2; g2.sKs = L; g2.cd = cdb; g2.sCd = L;
    g2.auxf = W2; g2.ldax = H; g2.sAuxf = HD; g2.clp = wdc + (L-1); g2.sClp = L;
    g2.Cf = out2; g2.sCf = HD;

    wnext_gemm<<<dim3(4,8,8), 256, 0, stream>>>(g1, g2);
  }
}